// Round 6
// baseline (324.002 us; speedup 1.0000x reference)
//
#include <hip/hip_runtime.h>

#define Fdim 128
#define Bsz  8192
#define Pn   6
#define EPSI 1e-5f
#define X2P 136       // x2 tile pitch (halves): mult-of-8 for b128 alignment; x2f reads are rare
#define X1P 72        // x1 half-tile pitch: mult-of-8; 4-way on x1f reads = 1.58x on ~0.7% of cycles

typedef _Float16 half8  __attribute__((ext_vector_type(8)));
typedef _Float16 half4t __attribute__((ext_vector_type(4)));
typedef float    float4t  __attribute__((ext_vector_type(4)));
typedef float    float16t __attribute__((ext_vector_type(16)));

__constant__ int PAIR_A[6] = {0,0,0,1,1,2};
__constant__ int PAIR_B[6] = {1,2,3,2,3,3};

// ---------------------------------------------------------------------------
// Kernel 1: W [128 x 16384] fp32 -> f16 B-fragments for mfma_f32_32x32x16_f16.
// lane holds B[k = c16*16 + (lane>>5)*8 + jj][n = nt*32 + (lane&31)], jj=0..7.
// Wws half8 index = c16*256 + nt*64 + lane  (c16 = k-chunk of 16, 0..1023).
// Also zero-inits ssum/ssq (block 1023) so no separate memset dispatch.
// ---------------------------------------------------------------------------
__global__ __launch_bounds__(256) void wprep(const float* __restrict__ W,
                                             _Float16* __restrict__ Wws,
                                             float* __restrict__ szero) {
    int t    = blockIdx.x * 256 + threadIdx.x;  // 0..262143 = 1024 c16 * 4 nt * 64 lane
    int c16  = t >> 8;
    int r    = t & 255;
    int nt   = r >> 6;
    int lane = r & 63;
    int q2   = lane >> 5;
    int o    = nt * 32 + (lane & 31);
    const float4t* src = (const float4t*)(W + (size_t)o * 16384 + c16 * 16 + q2 * 8);
    float4t a0 = src[0];
    float4t a1 = src[1];
    half8 h;
    h[0] = (_Float16)a0[0]; h[1] = (_Float16)a0[1];
    h[2] = (_Float16)a0[2]; h[3] = (_Float16)a0[3];
    h[4] = (_Float16)a1[0]; h[5] = (_Float16)a1[1];
    h[6] = (_Float16)a1[2]; h[7] = (_Float16)a1[3];
    *(half8*)(Wws + (size_t)t * 8) = h;
    if (blockIdx.x == 1023) {
        // zero 1536 floats of ssum/ssq (6 per thread)
        for (int z = 0; z < 6; ++z) szero[threadIdx.x + 256 * z] = 0.f;
    }
}

// ---------------------------------------------------------------------------
// Kernel 2: per (pair, 128-row m-block, 64-col n-half) GEMM, 32x32x16 MFMA.
// Wave w owns m-tile rows [w*32, w*32+32) x 2 n-tiles of 32. On-the-fly A:
// a[jj] = x1[m,i] * x2[m, jc*16 + q2*8 + jj]  (4 pk_mul per 2 MFMAs = 1/2 the
// 16x16 path's per-FLOP VALU; W bytes/FLOP also halved). x2 full tile + x1
// i-halved in LDS (53 KB -> 3 blocks/CU; grid 768 = one round, no tail).
// ---------------------------------------------------------------------------
__global__ __launch_bounds__(256, 3) void gemm(const float* __restrict__ x,
                                               const _Float16* __restrict__ Wws,
                                               _Float16* __restrict__ yws,
                                               float* __restrict__ ssum,
                                               float* __restrict__ ssq) {
    __shared__ _Float16 x2t[128 * X2P];    // 34816 B
    __shared__ _Float16 x1th[128 * X1P];   // 18432 B

    int bid  = blockIdx.x;
    int p    = bid >> 7;
    int rem  = bid & 127;
    int mblk = rem >> 1;
    int nh   = rem & 1;
    int m0   = mblk * 128;
    int v1   = PAIR_A[p];
    int v2   = PAIR_B[p];
    int tid  = threadIdx.x;

    // ---- stage x2 tile (full 128x128, fp32 -> f16) ------------------------
    {
        const float4t* s2p = (const float4t*)(x + ((size_t)v2 * Bsz + m0) * Fdim);
        for (int it = 0; it < 16; ++it) {
            int idx = it * 256 + tid;
            int row = idx >> 5;
            int col = (idx & 31) * 4;
            float4t b = s2p[idx];
            half4t h2; h2[0]=(_Float16)b[0]; h2[1]=(_Float16)b[1];
                       h2[2]=(_Float16)b[2]; h2[3]=(_Float16)b[3];
            *(half4t*)&x2t[row * X2P + col] = h2;
        }
    }

    int lane  = tid & 63;
    int w     = tid >> 6;
    int ol32  = lane & 31;
    int q2    = lane >> 5;
    int rbase = w * 32;                 // wave's m-tile
    int ntg0  = nh * 2;                 // global 32-wide n-tiles
    int ntg1  = ntg0 + 1;

    float16t acc0 = {0.f}, acc1 = {0.f};
#pragma unroll
    for (int z = 0; z < 16; ++z) { acc0[z] = 0.f; acc1[z] = 0.f; }

    const half8* wb = (const half8*)Wws;
    const size_t woff0 = (size_t)ntg0 * 64 + lane;   // half8 units within a c16 group
    const size_t woff1 = (size_t)ntg1 * 64 + lane;
    const float* x1src = x + ((size_t)v1 * Bsz + m0) * Fdim;

    for (int kh = 0; kh < 2; ++kh) {
        if (kh) __syncthreads();
        // ---- stage x1 half-tile: 128 rows x 64 i-cols ---------------------
        for (int it = 0; it < 8; ++it) {
            int idx = it * 256 + tid;
            int row = idx >> 4;
            int c4  = (idx & 15) * 4;
            float4t a = *(const float4t*)(x1src + (size_t)row * Fdim + kh * 64 + c4);
            half4t h1; h1[0]=(_Float16)a[0]; h1[1]=(_Float16)a[1];
                       h1[2]=(_Float16)a[2]; h1[3]=(_Float16)a[3];
            *(half4t*)&x1th[row * X1P + c4] = h1;
        }
        __syncthreads();

        int ibase = kh * 64;
        for (int jc = 0; jc < 8; ++jc) {   // j-chunks of 16
            // x2 fragment: constant across the whole 64-i sweep
            half8 x2f = *(const half8*)&x2t[(rbase + ol32) * X2P + jc * 16 + q2 * 8];

            // W prefetch pipeline, distance 2 (c16 = i*8 + jc)
            half8 bfa0 = wb[(size_t)((ibase + 0) * 8 + jc) * 256 + woff0];
            half8 bfa1 = wb[(size_t)((ibase + 0) * 8 + jc) * 256 + woff1];
            half8 bfb0 = wb[(size_t)((ibase + 1) * 8 + jc) * 256 + woff0];
            half8 bfb1 = wb[(size_t)((ibase + 1) * 8 + jc) * 256 + woff1];

            for (int i8 = 0; i8 < 8; ++i8) {
                half8 x1f = *(const half8*)&x1th[(rbase + ol32) * X1P + i8 * 8];
#pragma unroll
                for (int ii = 0; ii < 8; ++ii) {
                    int il  = i8 * 8 + ii;
                    int ipl = (il < 62) ? (il + 2) : 63;
                    half8 bn0 = wb[(size_t)((ibase + ipl) * 8 + jc) * 256 + woff0];
                    half8 bn1 = wb[(size_t)((ibase + ipl) * 8 + jc) * 256 + woff1];
                    _Float16 sc = x1f[ii];
                    half8 a = x2f * sc;            // 4 pk_mul shared by 2 MFMAs
                    acc0 = __builtin_amdgcn_mfma_f32_32x32x16_f16(a, bfa0, acc0, 0, 0, 0);
                    acc1 = __builtin_amdgcn_mfma_f32_32x32x16_f16(a, bfa1, acc1, 0, 0, 0);
                    bfa0 = bfb0; bfa1 = bfb1;
                    bfb0 = bn0;  bfb1 = bn1;
                }
            }
        }
    }

    // ---- epilogue: store y (f16) + per-o stats ----------------------------
    // C/D layout: col = lane&31, row_local = (reg&3) + 4*(lane>>5) + 8*(reg>>2)
    float sum0 = 0.f, sq0 = 0.f, sum1 = 0.f, sq1 = 0.f;
    int col0 = ntg0 * 32 + ol32;
    int col1 = ntg1 * 32 + ol32;
#pragma unroll
    for (int reg = 0; reg < 16; ++reg) {
        int rl = (reg & 3) + 4 * q2 + 8 * (reg >> 2);
        size_t row = (size_t)p * Bsz + m0 + rbase + rl;
        float v0 = acc0[reg];
        sum0 += v0; sq0 += v0 * v0;
        yws[row * Fdim + col0] = (_Float16)v0;
        float v1e = acc1[reg];
        sum1 += v1e; sq1 += v1e * v1e;
        yws[row * Fdim + col1] = (_Float16)v1e;
    }
    // lanes l and l+32 share a column and together cover all 32 rows
    sum0 += __shfl_xor(sum0, 32, 64);  sq0 += __shfl_xor(sq0, 32, 64);
    sum1 += __shfl_xor(sum1, 32, 64);  sq1 += __shfl_xor(sq1, 32, 64);
    if (q2 == 0) {
        atomicAdd(&ssum[p * Fdim + col0], sum0);
        atomicAdd(&ssq [p * Fdim + col0], sq0);
        atomicAdd(&ssum[p * Fdim + col1], sum1);
        atomicAdd(&ssq [p * Fdim + col1], sq1);
    }
}

// ---------------------------------------------------------------------------
// Kernel 3: BN (train-mode batch stats, biased var) + ReLU, f16 y -> fp32 out.
// ---------------------------------------------------------------------------
__global__ __launch_bounds__(256) void bnrelu(const _Float16* __restrict__ yws,
                                              const float* __restrict__ ssum,
                                              const float* __restrict__ ssq,
                                              const float* __restrict__ gamma,
                                              const float* __restrict__ beta,
                                              float* __restrict__ out) {
    __shared__ float gs[128], sh[128];
    size_t ebase = (size_t)blockIdx.x * 1024;
    int p = (int)(ebase >> 20);            // B*F = 2^20
    int t = threadIdx.x;
    if (t < 128) {
        float mean = ssum[p * Fdim + t] * (1.0f / 8192.0f);
        float var  = ssq [p * Fdim + t] * (1.0f / 8192.0f) - mean * mean;
        float g    = gamma[t] * rsqrtf(var + EPSI);
        gs[t] = g;
        sh[t] = beta[t] - g * mean;
    }
    __syncthreads();
    size_t e0 = ebase + (size_t)t * 4;
    int o0 = (int)(e0 & 127);
    half4t y = *(const half4t*)(yws + e0);
    float4t r;
#pragma unroll
    for (int l = 0; l < 4; ++l) {
        float v = fmaf(gs[o0 + l], (float)y[l], sh[o0 + l]);
        r[l] = v > 0.f ? v : 0.f;
    }
    *(float4t*)(out + e0) = r;
}

// ---------------------------------------------------------------------------
extern "C" void kernel_launch(void* const* d_in, const int* in_sizes, int n_in,
                              void* d_out, int out_size, void* d_ws, size_t ws_size,
                              hipStream_t stream) {
    const float* x     = (const float*)d_in[0];
    const float* W     = (const float*)d_in[1];
    // d_in[2] = linear bias b: mathematically cancelled by train-mode BN.
    const float* gamma = (const float*)d_in[3];
    const float* beta  = (const float*)d_in[4];
    float* out = (float*)d_out;

    char* ws = (char*)d_ws;
    _Float16* yws = (_Float16*)ws;                       // 6*8192*128*2 = 12,582,912 B
    _Float16* Wws = (_Float16*)(ws + 12582912);          // 128*16384*2  =  4,194,304 B
    float*    ssum = (float*)(ws + 16777216);            // 768 floats
    float*    ssq  = ssum + Pn * Fdim;                   // 768 floats

    wprep<<<1024, 256, 0, stream>>>(W, Wws, ssum);       // also zeroes ssum+ssq
    gemm<<<768, 256, 0, stream>>>(x, Wws, yws, ssum, ssq);
    bnrelu<<<6144, 256, 0, stream>>>(yws, ssum, ssq, gamma, beta, out);
}